// Round 2
// baseline (538.350 us; speedup 1.0000x reference)
//
#include <hip/hip_runtime.h>
#include <stdint.h>

#define N_POINTS   1048576
#define N_LEVELS   16
#define HASHMAP    524288u        // 1<<19
#define HASH_MASK  (HASHMAP - 1u)
#define PI1        2654435761u
#define PI2        805459861u

typedef float v2 __attribute__((ext_vector_type(2)));   // native 8B vector (nontemporal-compatible)

// int(16 * (32^(1/15))^i) for i in 0..15, replicated exactly from the reference
__constant__ float c_res[16] = {16.f,20.f,25.f,32.f,40.f,50.f,64.f,80.f,
                                101.f,128.f,161.f,203.f,256.f,322.f,406.f,512.f};
// phase order: alternate coarse/fine so adjacent-in-time levels' tables fit L2
__constant__ int c_perm[16] = {0,15,1,14,2,13,3,12,4,11,5,10,6,9,7,8};

__device__ __forceinline__ v2 enc_point_level(const float* __restrict__ x,
                                              const float* __restrict__ tables,
                                              int p, int level, float res) {
    float x0 = x[3*p+0], x1 = x[3*p+1], x2 = x[3*p+2];
    float sx = x0*res, sy = x1*res, sz = x2*res;
    int ix = (int)sx, iy = (int)sy, iz = (int)sz;   // trunc == floor for x>=0
    float fx = sx - (float)ix, fy = sy - (float)iy, fz = sz - (float)iz;
    uint32_t hx0 = (uint32_t)ix,       hx1 = hx0 + 1u;
    uint32_t hy0 = (uint32_t)iy * PI1, hy1 = hy0 + PI1;
    uint32_t hz0 = (uint32_t)iz * PI2, hz1 = hz0 + PI2;
    const v2* __restrict__ tab = (const v2*)tables + (size_t)level * HASHMAP;
    uint32_t e0 = hy0 ^ hz0, e1 = hy1 ^ hz0, e2 = hy0 ^ hz1, e3 = hy1 ^ hz1;
    uint32_t i0 = (hx0 ^ e0) & HASH_MASK;  // (0,0,0)
    uint32_t i1 = (hx1 ^ e0) & HASH_MASK;  // (1,0,0)
    uint32_t i2 = (hx0 ^ e1) & HASH_MASK;  // (0,1,0)
    uint32_t i3 = (hx1 ^ e1) & HASH_MASK;  // (1,1,0)
    uint32_t i4 = (hx0 ^ e2) & HASH_MASK;  // (0,0,1)
    uint32_t i5 = (hx1 ^ e2) & HASH_MASK;  // (1,0,1)
    uint32_t i6 = (hx0 ^ e3) & HASH_MASK;  // (0,1,1)
    uint32_t i7 = (hx1 ^ e3) & HASH_MASK;  // (1,1,1)
    // issue all 8 gathers back-to-back for MLP
    v2 f0 = tab[i0], f1 = tab[i1], f2 = tab[i2], f3 = tab[i3];
    v2 f4 = tab[i4], f5 = tab[i5], f6 = tab[i6], f7 = tab[i7];
    float wx1 = fx, wx0 = 1.f - fx;
    float wy1 = fy, wy0 = 1.f - fy;
    float wz1 = fz, wz0 = 1.f - fz;
    float w00 = wy0*wz0, w10 = wy1*wz0, w01 = wy0*wz1, w11 = wy1*wz1;
    float c0 = wx0*w00, c1 = wx1*w00, c2 = wx0*w10, c3 = wx1*w10;
    float c4 = wx0*w01, c5 = wx1*w01, c6 = wx0*w11, c7 = wx1*w11;
    v2 r;
    r.x = c0*f0.x + c1*f1.x + c2*f2.x + c3*f3.x + c4*f4.x + c5*f5.x + c6*f6.x + c7*f7.x;
    r.y = c0*f0.y + c1*f1.y + c2*f2.y + c3*f3.y + c4*f4.y + c5*f5.y + c6*f6.y + c7*f7.y;
    return r;
}

// Pass 1 (phased): blockIdx level-major -> whole device sweeps one level at a
// time -> that level's 4 MB table is per-XCD-L2-resident. Writes level-major
// workspace coalesced (v2/lane), nontemporal so it doesn't evict table lines.
__global__ __launch_bounds__(256) void hash_enc_phase(const float* __restrict__ x,
                                                      const float* __restrict__ tables,
                                                      v2* __restrict__ ws) {
    int level = c_perm[blockIdx.x >> 12];           // 4096 blocks per level
    int p = ((blockIdx.x & 4095) << 8) | threadIdx.x;
    v2 r = enc_point_level(x, tables, p, level, c_res[level]);
    __builtin_nontemporal_store(r, ws + (size_t)level * N_POINTS + p);
}

// Pass 2: (L, N, 2) -> (N, L*2) via LDS tile. 256 points x 16 levels per block.
// Pad row to 34 floats: stage-1 writes 2-way-aliased (free), stage-2 reads at
// the 4-access/bank b64 floor.
__global__ __launch_bounds__(256) void transpose_lvl(const v2* __restrict__ ws,
                                                     v2* __restrict__ out) {
    __shared__ float tile[256][34];
    int t = threadIdx.x;
    int p0 = blockIdx.x << 8;
    #pragma unroll
    for (int l = 0; l < 16; ++l) {
        v2 v = __builtin_nontemporal_load(ws + (size_t)l * N_POINTS + p0 + t);
        tile[t][2*l]   = v.x;
        tile[t][2*l+1] = v.y;
    }
    __syncthreads();
    #pragma unroll
    for (int k = 0; k < 16; ++k) {
        int j  = (k << 8) | t;          // v2 index within block's output
        int pl = j >> 4, c2 = j & 15;
        v2 v;
        v.x = tile[pl][2*c2];
        v.y = tile[pl][2*c2+1];
        __builtin_nontemporal_store(v, out + ((size_t)p0 << 4) + j);
    }
}

// Fallback if ws too small: fused, thread = (point, level) interleaved so the
// v2 output store is perfectly coalesced. Gathers mix all 16 levels (L2
// thrash) — slower, but correct with zero workspace.
__global__ __launch_bounds__(256) void hash_enc_fused(const float* __restrict__ x,
                                                      const float* __restrict__ tables,
                                                      v2* __restrict__ out) {
    int tid = blockIdx.x * 256 + threadIdx.x;       // 16M threads
    int level = tid & 15;
    int p = tid >> 4;
    v2 r = enc_point_level(x, tables, p, level, c_res[level]);
    out[tid] = r;
}

extern "C" void kernel_launch(void* const* d_in, const int* in_sizes, int n_in,
                              void* d_out, int out_size, void* d_ws, size_t ws_size,
                              hipStream_t stream) {
    const float* x      = (const float*)d_in[0];
    const float* tables = (const float*)d_in[1];
    size_t need = (size_t)N_LEVELS * N_POINTS * sizeof(v2);   // 128 MB
    if (ws_size >= need) {
        hash_enc_phase<<<dim3(65536), dim3(256), 0, stream>>>(x, tables, (v2*)d_ws);
        transpose_lvl<<<dim3(4096), dim3(256), 0, stream>>>((const v2*)d_ws, (v2*)d_out);
    } else {
        hash_enc_fused<<<dim3(65536), dim3(256), 0, stream>>>(x, tables, (v2*)d_out);
    }
}